// Round 16
// baseline (843.686 us; speedup 1.0000x reference)
//
#include <hip/hip_runtime.h>

typedef unsigned short u16;
typedef unsigned int u32;
typedef __bf16 bf16x8 __attribute__((ext_vector_type(8)));
typedef bf16x8 __attribute__((may_alias)) bf16x8a;   // TBAA-safe vector loads
typedef float f32x4 __attribute__((ext_vector_type(4)));
typedef _Float16 f16;
typedef _Float16 f16x2 __attribute__((ext_vector_type(2)));

#define BB 32
#define SS 1024
#define HH 128
#define DD 256

__device__ __forceinline__ float b2f(u16 u) {
    u32 v = ((u32)u) << 16;
    return __builtin_bit_cast(float, v);
}
__device__ __forceinline__ u16 f2b(float f) {
    u32 u = __builtin_bit_cast(u32, f);
    u32 r = (u + 0x7fffu + ((u >> 16) & 1u)) >> 16;   // RNE
    return (u16)r;
}
__device__ __forceinline__ float sig_fast(float x) {
    return __builtin_amdgcn_rcpf(1.0f + __builtin_amdgcn_exp2f(-1.4426950408889634f * x));
}
__device__ __forceinline__ float tanh_fast(float x) {
    return 2.0f * sig_fast(2.0f * x) - 1.0f;
}
// DPP lane-permute move (VALU pipe, no LDS). CTRLs used:
//   0xB1 = quad_perm(1,0,3,2)  = xor1      0x4E = quad_perm(2,3,0,1) = xor2
//   0x124 = row_ror:4          0x128 = row_ror:8   (16-lane-row rotations)
// 16-lane butterfly reduce: xor1, xor2 (quads uniform), then ror4 (+quad+1),
// ror8 (+quad+2,+3) — valid for any commutative/associative op.
template <int CTRL>
__device__ __forceinline__ float dpp_mov(float x) {
    return __builtin_bit_cast(float,
        __builtin_amdgcn_update_dpp(0, __builtin_bit_cast(int, x),
                                    CTRL, 0xF, 0xF, true));
}
// Raw workgroup barrier that drains ONLY the LDS pipe (lgkmcnt). Unlike
// __syncthreads(), which emits s_waitcnt vmcnt(0) lgkmcnt(0) before
// s_barrier, this leaves global loads/stores in flight across the barrier
// (r4: confirmed real, −160 cyc/step). "memory" clobber pins compiler-side
// ordering of the LDS ops. (Used in the SCAN only — r12 showed bundling it
// into attn correlated with a regression.)
__device__ __forceinline__ void lds_barrier() {
    asm volatile("s_waitcnt lgkmcnt(0)\n\ts_barrier" ::: "memory");
}

// ---------------------------------------------------------------------------
// All 7 weight conversions in ONE kernel (each matrix = 65536 elements).
// mode 0: gate-perm (row g*128+u -> u*4+g), bf16   (Wih for xg GEMM)
// mode 1: gate-perm, f16                           (Whh for scan dot2)
// mode 2: plain, bf16                              (Wq/Wk/Wv)
// ---------------------------------------------------------------------------
__global__ __launch_bounds__(256) void conv_weights(
    const float* __restrict__ fwWih, const float* __restrict__ bwWih,
    const float* __restrict__ fwWhh, const float* __restrict__ bwWhh,
    const float* __restrict__ Wq, const float* __restrict__ Wk,
    const float* __restrict__ Wv,
    u16* __restrict__ wfih, u16* __restrict__ wbih, u16* __restrict__ whhf,
    u16* __restrict__ wq, u16* __restrict__ wk, u16* __restrict__ wv)
{
    const int which = blockIdx.y;
    const float* src; u16* dst; int mode;
    switch (which) {
        case 0: src = fwWih; dst = wfih;              mode = 0; break;
        case 1: src = bwWih; dst = wbih;              mode = 0; break;
        case 2: src = fwWhh; dst = whhf;              mode = 1; break;
        case 3: src = bwWhh; dst = whhf + 512 * 128;  mode = 1; break;
        case 4: src = Wq;    dst = wq;                mode = 2; break;
        case 5: src = Wk;    dst = wk;                mode = 2; break;
        default: src = Wv;   dst = wv;                mode = 2; break;
    }
    for (int i = blockIdx.x * 256 + threadIdx.x; i < 65536 / 4; i += 32 * 256) {
        float4 v = ((const float4*)src)[i];
        ushort4 o;
        if (mode == 1) {
            o.x = __builtin_bit_cast(u16, (f16)v.x);
            o.y = __builtin_bit_cast(u16, (f16)v.y);
            o.z = __builtin_bit_cast(u16, (f16)v.z);
            o.w = __builtin_bit_cast(u16, (f16)v.w);
        } else {
            o.x = f2b(v.x); o.y = f2b(v.y); o.z = f2b(v.z); o.w = f2b(v.w);
        }
        if (mode == 2) {
            ((ushort4*)dst)[i] = o;
        } else {
            int r = i >> 5, c4 = i & 31;                 // [512][128] view
            int rp = ((r & 127) << 2) | (r >> 7);        // u*4 + g
            *(ushort4*)&dst[rp * 128 + c4 * 4] = o;
        }
    }
}

// ---------------------------------------------------------------------------
// Shared MFMA GEMM core: C[M,N] = A[M,K]*Bt[N,K]^T, fp32 acc, bf16 out.
// 128x128 tile, BK=64, 256 thr = 4 waves (2x2), wave = 64x64.
// AFP32: A is fp32 in global, converted to bf16 during LDS staging.
// MODE 0: row-major store, no bias. MODE 1: xg store [s][b][col] + bias
// (bias index un-permuted since cols are gate-interleaved).
// TRANSGRID: remap the fixed (256,2,z) launch grid so blockIdx.x indexes N
// and blockIdx.y indexes M (for the M=256 x N=32768 v^T GEMM).
// ---------------------------------------------------------------------------
template <int MODE, int AFP32, int TRANSGRID = 0>
__device__ __forceinline__ void gemm_core(
    const void* __restrict__ Araw, const u16* __restrict__ Bt,
    const float* __restrict__ bias1, const float* __restrict__ bias2,
    u16* __restrict__ Cout, int K, int N)
{
    __shared__ u16 As[128 * 72];
    __shared__ u16 Bs[128 * 72];
    const int tid = threadIdx.x;
    const int lane = tid & 63, wave = tid >> 6;
    const int wm = wave >> 1, wn = wave & 1;
    const int lo = lane & 15, hi = lane >> 4;
    const int m0 = (TRANSGRID ? blockIdx.y : blockIdx.x) * 128;
    const int n0 = (TRANSGRID ? blockIdx.x : blockIdx.y) * 128;

    f32x4 acc[4][4] = {};

    for (int k0 = 0; k0 < K; k0 += 64) {
        __syncthreads();
#pragma unroll
        for (int i = 0; i < 4; i++) {
            int c = tid + 256 * i;
            int row = c >> 3, kc = (c & 7) * 8;
            if (AFP32) {
                const float* ap = (const float*)Araw + (size_t)(m0 + row) * K + k0 + kc;
                float4 v0 = *(const float4*)ap;
                float4 v1 = *(const float4*)(ap + 4);
                uint4 o;
                o.x = (u32)f2b(v0.x) | ((u32)f2b(v0.y) << 16);
                o.y = (u32)f2b(v0.z) | ((u32)f2b(v0.w) << 16);
                o.z = (u32)f2b(v1.x) | ((u32)f2b(v1.y) << 16);
                o.w = (u32)f2b(v1.z) | ((u32)f2b(v1.w) << 16);
                *(uint4*)&As[row * 72 + kc] = o;
            } else {
                *(uint4*)&As[row * 72 + kc] =
                    *(const uint4*)&((const u16*)Araw)[(size_t)(m0 + row) * K + k0 + kc];
            }
            *(uint4*)&Bs[row * 72 + kc] =
                *(const uint4*)&Bt[(size_t)(n0 + row) * K + k0 + kc];
        }
        __syncthreads();
#pragma unroll
        for (int ks = 0; ks < 2; ks++) {
            bf16x8 af[4], bfr[4];
#pragma unroll
            for (int i = 0; i < 4; i++)
                af[i] = *(const bf16x8a*)&As[(wm * 64 + i * 16 + lo) * 72 + ks * 32 + hi * 8];
#pragma unroll
            for (int j = 0; j < 4; j++)
                bfr[j] = *(const bf16x8a*)&Bs[(wn * 64 + j * 16 + lo) * 72 + ks * 32 + hi * 8];
#pragma unroll
            for (int i = 0; i < 4; i++)
#pragma unroll
                for (int j = 0; j < 4; j++)
                    acc[i][j] = __builtin_amdgcn_mfma_f32_16x16x32_bf16(
                        af[i], bfr[j], acc[i][j], 0, 0, 0);
        }
    }
#pragma unroll
    for (int j = 0; j < 4; j++) {
        int col = n0 + wn * 64 + j * 16 + lo;
        float bsum = 0.f;
        if (MODE == 1) {
            int co = ((col & 3) << 7) | (col >> 2);   // un-permute for bias lookup
            bsum = bias1[co] + bias2[co];
        }
#pragma unroll
        for (int i = 0; i < 4; i++) {
            int row0 = m0 + wm * 64 + i * 16 + hi * 4;
#pragma unroll
            for (int r = 0; r < 4; r++) {
                float v = acc[i][j][r] + bsum;
                if (MODE == 1) {
                    int row = row0 + r;                 // = b*1024 + s
                    int sidx = row & 1023, bidx = row >> 10;
                    Cout[(size_t)sidx * (BB * 512) + bidx * 512 + col] = f2b(v);
                } else {
                    Cout[(size_t)(row0 + r) * N + col] = f2b(v);
                }
            }
        }
    }
}

// both xg directions in one launch (blockIdx.z = dir); A = x in fp32
__global__ __launch_bounds__(256) void gemm_xg(
    const float* __restrict__ A, const u16* __restrict__ Bt_f,
    const u16* __restrict__ Bt_b,
    const float* __restrict__ f_bih, const float* __restrict__ f_bhh,
    const float* __restrict__ b_bih, const float* __restrict__ b_bhh,
    u16* __restrict__ xg)
{
    const int dir = blockIdx.z;
    gemm_core<1, 1>(A, dir ? Bt_b : Bt_f,
                    dir ? b_bih : f_bih, dir ? b_bhh : f_bhh,
                    xg + (size_t)dir * SS * BB * 512, 128, 512);
}

// q,k,v^T in one launch (blockIdx.z selects).
// z=0/1: q,k = h @ W^T -> [32768][256] row-major (grid x=M-blocks, y=N-blocks).
// z=2:   vT = Wv @ h^T -> [256][32768] d-major (TRANSGRID: x=N-blocks,
//        y=M-blocks) — eliminates the separate transpose_v pass entirely
//        (r11: killed 48 MB of traffic + a launch; confirmed −20 us).
__global__ __launch_bounds__(256) void gemm_qkv(
    const u16* __restrict__ A, const u16* __restrict__ Wq,
    const u16* __restrict__ Wk, const u16* __restrict__ Wv,
    u16* __restrict__ qb, u16* __restrict__ kb, u16* __restrict__ vT)
{
    const int z = blockIdx.z;
    if (z == 2) {
        gemm_core<0, 0, 1>(Wv, A, nullptr, nullptr, vT, 256, BB * SS);
    } else {
        const u16* Bt = (z == 0) ? Wq : Wk;
        u16* out = (z == 0) ? qb : kb;
        gemm_core<0, 0>(A, Bt, nullptr, nullptr, out, 256, 256);
    }
}

// ---------------------------------------------------------------------------
// Split-K dot2 LSTM scan v6 (the verified best: ~530 us, step 1243 cyc,
// VGPR 132 = weights resident). 64 WGs (one per (dir,b) sequence),
// 256 thr = 4 waves = 1 wave/SIMD, waves_per_eu(1,1) — the only config
// whose regalloc verifiably holds the 128 weight words.
//
// Structural-floor verdict after r6-r9: same-chain TLP shares the serial
// chain (r1/r3); cross-chain wave-TLP spills at the (2,2) budget (r6);
// cross-chain ILP spills at the 132-reg wall AND halves CUs (r7); MFMA
// variants either waste 16x M-rows (r8) or starve CUs + uncoalesce xg
// (r9). v6's step = ds_read(h) -> 128 fdot2 -> DPP reduce -> activation
// chain -> ds_write -> lds_barrier, with 64 CUs active.
// ---------------------------------------------------------------------------
__global__ __launch_bounds__(256)
__attribute__((amdgpu_waves_per_eu(1, 1)))
void lstm_scan_sk(
    const u16* __restrict__ Whh_h,   // [2][512][128] f16, rows permuted
    const u16* __restrict__ xg,      // [2][S][B][512] bf16, cols permuted
    u16* __restrict__ hout)          // [B][S][256] bf16
{
    const int wg = blockIdx.x;       // 0..63
    const int dir = wg >> 5, b = wg & 31;
    const int t_ = threadIdx.x;      // 0..255
    const int u = t_ >> 1;           // unit 0..127
    const int kh = t_ & 1;           // K-half

    // resident weights: rows 4u..4u+3, K-half kh -> 128 u32 in VGPRs.
    u32 w[4][32];
    {
        const volatile u32* vp = (const volatile u32*)(Whh_h + (size_t)dir * 512 * 128);
#pragma unroll
        for (int g = 0; g < 4; g++) {
            int base = ((4 * u + g) * 128 + kh * 64) >> 1;   // u32 index
#pragma unroll
            for (int k = 0; k < 32; k++) w[g][k] = vp[base + k];
        }
    }

    __shared__ __align__(16) u16 hbuf[2][128];   // f16 bits, double-buffered
    if (t_ < 128) hbuf[0][t_] = 0;
    float c = 0.0f;

    const u16* xgp = xg + (size_t)dir * SS * (BB * 512) + (size_t)b * 512 + 4 * u;
    u16* hop = hout + (size_t)b * SS * DD + dir * HH + u;

    int s = dir ? (SS - 1) : 0;
    const int d1 = dir ? -1 : 1;
    uint2 nxA = *(const uint2*)&xgp[(size_t)s * (BB * 512)];         // step 0
    uint2 nxB = *(const uint2*)&xgp[(size_t)(s + d1) * (BB * 512)];  // step 1
    lds_barrier();

    // one LSTM step; nx holds this step's xg, refilled for step t+2.
    auto body = [&](uint2& nx, int parity) {
        uint2 xv = nx;                      // counted vmcnt wait (~2 steps slack)
        int sp = s + 2 * d1;                // depth-2 prefetch, issued EARLY
        if ((unsigned)sp < SS)
            nx = *(const uint2*)&xgp[(size_t)sp * (BB * 512)];

        const uint4* hb = (const uint4*)&hbuf[parity][kh * 64];
        float g0 = 0.f, g1 = 0.f, g2 = 0.f, g3 = 0.f;   // 4 chains (one per gate)
#pragma unroll
        for (int cc = 0; cc < 8; cc++) {
            uint4 hh = hb[cc];                           // broadcast read (free)
            u32 hv[4] = {hh.x, hh.y, hh.z, hh.w};
#pragma unroll
            for (int j = 0; j < 4; j++) {
                f16x2 hp = __builtin_bit_cast(f16x2, hv[j]);
                g0 = __builtin_amdgcn_fdot2(hp, __builtin_bit_cast(f16x2, w[0][4 * cc + j]), g0, false);
                g1 = __builtin_amdgcn_fdot2(hp, __builtin_bit_cast(f16x2, w[1][4 * cc + j]), g1, false);
                g2 = __builtin_amdgcn_fdot2(hp, __builtin_bit_cast(f16x2, w[2][4 * cc + j]), g2, false);
                g3 = __builtin_amdgcn_fdot2(hp, __builtin_bit_cast(f16x2, w[3][4 * cc + j]), g3, false);
            }
        }
        // cross-half butterfly reduce on the VALU pipe: ONE DPP level (lane^1)
        g0 += dpp_mov<0xB1>(g0);
        g1 += dpp_mov<0xB1>(g1);
        g2 += dpp_mov<0xB1>(g2);
        g3 += dpp_mov<0xB1>(g3);
        // add xg (gates i,f,g~,o = permuted cols 4u..4u+3)
        g0 += b2f((u16)(xv.x & 0xffff)); g1 += b2f((u16)(xv.x >> 16));
        g2 += b2f((u16)(xv.y & 0xffff)); g3 += b2f((u16)(xv.y >> 16));

        c = fmaf(sig_fast(g1), c, sig_fast(g0) * tanh_fast(g2));
        float h = sig_fast(g3) * tanh_fast(c);

        if (kh == 0)
            hbuf[parity ^ 1][u] = __builtin_bit_cast(u16, (f16)h);
        else
            hop[(size_t)s * DD] = f2b(h);
        lds_barrier();                      // LDS-only drain; vmem stays in flight
        s += d1;
    };

    for (int t = 0; t < SS; t += 2) {
        body(nxA, 0);
        body(nxB, 1);
    }
}

// ---------------------------------------------------------------------------
// Flash attention v3 (single change vs r15: KV tile 32 -> 64). Halves the
// per-tile fixed costs (2 barrier+drain events, the 4-level DPP reduce
// chains, the 64-mult o-rescale pass) at the SAME total MFMA/exp2/staging
// work. Occupancy cost is zero: LDS 42->80 KB caps residency at 2 WGs/CU,
// but the 512-WG grid on 256 CUs is exactly 2/CU already. PV handles the
// two k-slices (0-31, 32-63) with pa/bv fragment pairs at LDS offset +32 —
// A and B share the lane->k rule, so the contraction is permutation-safe.
// Ps remains same-wave-only (own 16-row stripe) -> still no mid-tile
// barrier (r15 verified). Pads: Ks row 264, Vs/Ps row 72 (stride mod 32
// dwords = 4 -> <=2-way banks, free). XCD swizzle (T1), DPP softmax,
// s_setprio (T5), V from d-major vT. f32 out.
// ---------------------------------------------------------------------------
__global__ __launch_bounds__(256) void attn_kernel(
    const u16* __restrict__ q, const u16* __restrict__ k,
    const u16* __restrict__ vT, float* __restrict__ out)
{
    __shared__ u16 Ks[64 * 264];
    __shared__ u16 Vs[256 * 72];
    __shared__ u16 Ps[64 * 72];
    const int bid = blockIdx.x;                  // 0..511
    const int b = (bid & 7) * 4 + (bid >> 7);    // batch: XCD-pinned
    const int q0 = ((bid >> 3) & 15) * 64;       // q tile
    const int tid = threadIdx.x, wave = tid >> 6, lane = tid & 63;
    const int lo = lane & 15, hi = lane >> 4;
    const float c1 = 0.09016844005556021f;  // log2(e)/16

    bf16x8 qf[8];
    {
        const u16* qp = q + ((size_t)b * SS + q0 + wave * 16 + lo) * DD;
#pragma unroll
        for (int ks = 0; ks < 8; ks++)
            qf[ks] = *(const bf16x8a*)&qp[ks * 32 + hi * 8];
    }
    float m_i[4] = {-1e30f, -1e30f, -1e30f, -1e30f};
    float l_i[4] = {0.f, 0.f, 0.f, 0.f};
    f32x4 o[16] = {};

    for (int t0 = 0; t0 < SS; t0 += 64) {
        __syncthreads();
#pragma unroll
        for (int i = 0; i < 8; i++) {
            int c = tid + 256 * i;
            {
                int row = c >> 5, dc = (c & 31) * 8;     // 64 rows x 256 u16
                *(uint4*)&Ks[row * 264 + dc] =
                    *(const uint4*)&k[((size_t)b * SS + t0 + row) * DD + dc];
            }
            {
                int d = c >> 3, sc = (c & 7) * 8;        // 256 rows x 64 u16
                *(uint4*)&Vs[d * 72 + sc] =
                    *(const uint4*)&vT[(size_t)d * (BB * SS) + b * SS + t0 + sc];
            }
        }
        __syncthreads();

        f32x4 sacc[4] = {};
        __builtin_amdgcn_s_setprio(1);
#pragma unroll
        for (int ks = 0; ks < 8; ks++) {
#pragma unroll
            for (int j = 0; j < 4; j++) {
                bf16x8 bfr = *(const bf16x8a*)&Ks[(j * 16 + lo) * 264 + ks * 32 + hi * 8];
                sacc[j] = __builtin_amdgcn_mfma_f32_16x16x32_bf16(qf[ks], bfr, sacc[j], 0, 0, 0);
            }
        }
        __builtin_amdgcn_s_setprio(0);

        float tt[4][4];
#pragma unroll
        for (int j = 0; j < 4; j++)
#pragma unroll
            for (int r = 0; r < 4; r++) tt[j][r] = sacc[j][r] * c1;
        // 16-lane max reduce on the VALU pipe (DPP): xor1, xor2, ror4, ror8
        float rm[4];
#pragma unroll
        for (int r = 0; r < 4; r++)
            rm[r] = fmaxf(fmaxf(tt[0][r], tt[1][r]), fmaxf(tt[2][r], tt[3][r]));
#pragma unroll
        for (int r = 0; r < 4; r++) rm[r] = fmaxf(rm[r], dpp_mov<0xB1>(rm[r]));
#pragma unroll
        for (int r = 0; r < 4; r++) rm[r] = fmaxf(rm[r], dpp_mov<0x4E>(rm[r]));
#pragma unroll
        for (int r = 0; r < 4; r++) rm[r] = fmaxf(rm[r], dpp_mov<0x124>(rm[r]));
#pragma unroll
        for (int r = 0; r < 4; r++) rm[r] = fmaxf(rm[r], dpp_mov<0x128>(rm[r]));
        float al[4], rs[4];
#pragma unroll
        for (int r = 0; r < 4; r++) {
            float mn = fmaxf(m_i[r], rm[r]);
            al[r] = __builtin_amdgcn_exp2f(m_i[r] - mn);
            m_i[r] = mn;
            rs[r] = 0.f;
        }
#pragma unroll
        for (int j = 0; j < 4; j++)
#pragma unroll
            for (int r = 0; r < 4; r++) {
                float p = __builtin_amdgcn_exp2f(tt[j][r] - m_i[r]);
                rs[r] += p;
                Ps[(wave * 16 + hi * 4 + r) * 72 + j * 16 + lo] = f2b(p);
            }
        // 16-lane sum reduce on the VALU pipe (DPP)
#pragma unroll
        for (int r = 0; r < 4; r++) rs[r] += dpp_mov<0xB1>(rs[r]);
#pragma unroll
        for (int r = 0; r < 4; r++) rs[r] += dpp_mov<0x4E>(rs[r]);
#pragma unroll
        for (int r = 0; r < 4; r++) rs[r] += dpp_mov<0x124>(rs[r]);
#pragma unroll
        for (int r = 0; r < 4; r++) rs[r] += dpp_mov<0x128>(rs[r]);
#pragma unroll
        for (int r = 0; r < 4; r++) l_i[r] = l_i[r] * al[r] + rs[r];
#pragma unroll
        for (int nt = 0; nt < 16; nt++) {
            o[nt][0] *= al[0]; o[nt][1] *= al[1];
            o[nt][2] *= al[2]; o[nt][3] *= al[3];
        }
        // NO barrier here: Ps RAW is same-wave only (r15 verified); the DS
        // pipe is in-order per wave and the compiler inserts the lgkmcnt.
        bf16x8 pa0 = *(const bf16x8a*)&Ps[(wave * 16 + lo) * 72 + hi * 8];
        bf16x8 pa1 = *(const bf16x8a*)&Ps[(wave * 16 + lo) * 72 + 32 + hi * 8];
        __builtin_amdgcn_s_setprio(1);
#pragma unroll
        for (int nt = 0; nt < 16; nt++) {
            bf16x8 bv0 = *(const bf16x8a*)&Vs[(nt * 16 + lo) * 72 + hi * 8];
            o[nt] = __builtin_amdgcn_mfma_f32_16x16x32_bf16(pa0, bv0, o[nt], 0, 0, 0);
            bf16x8 bv1 = *(const bf16x8a*)&Vs[(nt * 16 + lo) * 72 + 32 + hi * 8];
            o[nt] = __builtin_amdgcn_mfma_f32_16x16x32_bf16(pa1, bv1, o[nt], 0, 0, 0);
        }
        __builtin_amdgcn_s_setprio(0);
    }
    float inv[4];
#pragma unroll
    for (int r = 0; r < 4; r++) inv[r] = __builtin_amdgcn_rcpf(l_i[r]);
#pragma unroll
    for (int nt = 0; nt < 16; nt++)
#pragma unroll
        for (int r = 0; r < 4; r++) {
            int row = q0 + wave * 16 + hi * 4 + r;
            int col = nt * 16 + lo;
            out[((size_t)b * SS + row) * DD + col] = o[nt][r] * inv[r];
        }
}

// ---------------------------------------------------------------------------
extern "C" void kernel_launch(void* const* d_in, const int* in_sizes, int n_in,
                              void* d_out, int out_size, void* d_ws, size_t ws_size,
                              hipStream_t stream)
{
    (void)in_sizes; (void)n_in; (void)out_size;
    const float* x      = (const float*)d_in[0];
    const float* fw_Wih = (const float*)d_in[1];
    const float* fw_Whh = (const float*)d_in[2];
    const float* fw_bih = (const float*)d_in[3];
    const float* fw_bhh = (const float*)d_in[4];
    const float* bw_Wih = (const float*)d_in[5];
    const float* bw_Whh = (const float*)d_in[6];
    const float* bw_bih = (const float*)d_in[7];
    const float* bw_bhh = (const float*)d_in[8];
    const float* Wq = (const float*)d_in[9];
    const float* Wk = (const float*)d_in[10];
    const float* Wv = (const float*)d_in[11];

    // Workspace layout (total 143,523,840 B; ws proven >= 201 MB in r1/r2):
    //   [0, 67108864)    xg bf16 [2][S][B][512], cols gate-interleaved
    //                    (dead after scan)
    //   +67108864        h   bf16 [32768][256]
    //   +83886080        qb   +100663296 kb   +117440512 vT [256][32768]
    //   +142606336       weights: fwWih_p, bwWih_p, wq, wk, wv (bf16),
    //                    Whh f16 permuted [2][512][128]
    if (ws_size < 143523840ULL) return;

    char* ws = (char*)d_ws;
    u16* xg  = (u16*)ws;
    u16* h   = (u16*)(ws + 67108864);
    u16* qb  = (u16*)(ws + 83886080);
    u16* kb  = (u16*)(ws + 100663296);
    u16* vT  = (u16*)(ws + 117440512);
    u16* wfih16 = (u16*)(ws + 142606336);
    u16* wbih16 = (u16*)(ws + 142606336 + 131072);
    u16* wq16   = (u16*)(ws + 142606336 + 262144);
    u16* wk16   = (u16*)(ws + 142606336 + 393216);
    u16* wv16   = (u16*)(ws + 142606336 + 524288);
    u16* whhf16 = (u16*)(ws + 142606336 + 655360);   // [2][512][128] f16

    conv_weights<<<dim3(32, 7), 256, 0, stream>>>(
        fw_Wih, bw_Wih, fw_Whh, bw_Whh, Wq, Wk, Wv,
        wfih16, wbih16, whhf16, wq16, wk16, wv16);

    // xg = x @ Wih_p^T + biases -> [s][b][512] permuted-col layout (both dirs);
    // x is fp32, converted to bf16 during LDS staging
    gemm_xg<<<dim3(256, 4, 2), 256, 0, stream>>>(
        x, wfih16, wbih16, fw_bih, fw_bhh, bw_bih, bw_bhh, xg);
    // split-K dot2 scan v6 (verified best: ~530 us), 64 WGs
    lstm_scan_sk<<<64, 256, 0, stream>>>(whhf16, xg, h);
    // q,k (row-major) and v^T (d-major, direct — no transpose pass)
    gemm_qkv<<<dim3(256, 2, 3), 256, 0, stream>>>(h, wq16, wk16, wv16, qb, kb, vT);
    // fused attention -> out fp32 (KV tile 64; r15 + halved fixed costs)
    attn_kernel<<<512, 256, 0, stream>>>(qb, kb, vT, (float*)d_out);
}

// Round 17
// 734.875 us; speedup vs baseline: 1.1481x; 1.1481x over previous
//
#include <hip/hip_runtime.h>

typedef unsigned short u16;
typedef unsigned int u32;
typedef __bf16 bf16x8 __attribute__((ext_vector_type(8)));
typedef bf16x8 __attribute__((may_alias)) bf16x8a;   // TBAA-safe vector loads
typedef float f32x4 __attribute__((ext_vector_type(4)));
typedef _Float16 f16;
typedef _Float16 f16x2 __attribute__((ext_vector_type(2)));

#define BB 32
#define SS 1024
#define HH 128
#define DD 256

__device__ __forceinline__ float b2f(u16 u) {
    u32 v = ((u32)u) << 16;
    return __builtin_bit_cast(float, v);
}
__device__ __forceinline__ u16 f2b(float f) {
    u32 u = __builtin_bit_cast(u32, f);
    u32 r = (u + 0x7fffu + ((u >> 16) & 1u)) >> 16;   // RNE
    return (u16)r;
}
__device__ __forceinline__ float sig_fast(float x) {
    return __builtin_amdgcn_rcpf(1.0f + __builtin_amdgcn_exp2f(-1.4426950408889634f * x));
}
__device__ __forceinline__ float tanh_fast(float x) {
    return 2.0f * sig_fast(2.0f * x) - 1.0f;
}
// DPP lane-permute move (VALU pipe, no LDS). CTRLs used:
//   0xB1 = quad_perm(1,0,3,2)  = xor1      0x4E = quad_perm(2,3,0,1) = xor2
//   0x124 = row_ror:4          0x128 = row_ror:8   (16-lane-row rotations)
// 16-lane butterfly reduce: xor1, xor2 (quads uniform), then ror4 (+quad+1),
// ror8 (+quad+2,+3) — valid for any commutative/associative op.
template <int CTRL>
__device__ __forceinline__ float dpp_mov(float x) {
    return __builtin_bit_cast(float,
        __builtin_amdgcn_update_dpp(0, __builtin_bit_cast(int, x),
                                    CTRL, 0xF, 0xF, true));
}
// Raw workgroup barrier that drains ONLY the LDS pipe (lgkmcnt). Unlike
// __syncthreads(), which emits s_waitcnt vmcnt(0) lgkmcnt(0) before
// s_barrier, this leaves global loads/stores in flight across the barrier
// (r4: confirmed real, −160 cyc/step). "memory" clobber pins compiler-side
// ordering of the LDS ops. (Used in the SCAN only — r12 showed bundling it
// into attn correlated with a regression.)
__device__ __forceinline__ void lds_barrier() {
    asm volatile("s_waitcnt lgkmcnt(0)\n\ts_barrier" ::: "memory");
}

// ---------------------------------------------------------------------------
// All 7 weight conversions in ONE kernel (each matrix = 65536 elements).
// mode 0: gate-perm (row g*128+u -> u*4+g), bf16   (Wih for xg GEMM)
// mode 1: gate-perm, f16                           (Whh for scan dot2)
// mode 2: plain, bf16                              (Wq/Wk/Wv)
// ---------------------------------------------------------------------------
__global__ __launch_bounds__(256) void conv_weights(
    const float* __restrict__ fwWih, const float* __restrict__ bwWih,
    const float* __restrict__ fwWhh, const float* __restrict__ bwWhh,
    const float* __restrict__ Wq, const float* __restrict__ Wk,
    const float* __restrict__ Wv,
    u16* __restrict__ wfih, u16* __restrict__ wbih, u16* __restrict__ whhf,
    u16* __restrict__ wq, u16* __restrict__ wk, u16* __restrict__ wv)
{
    const int which = blockIdx.y;
    const float* src; u16* dst; int mode;
    switch (which) {
        case 0: src = fwWih; dst = wfih;              mode = 0; break;
        case 1: src = bwWih; dst = wbih;              mode = 0; break;
        case 2: src = fwWhh; dst = whhf;              mode = 1; break;
        case 3: src = bwWhh; dst = whhf + 512 * 128;  mode = 1; break;
        case 4: src = Wq;    dst = wq;                mode = 2; break;
        case 5: src = Wk;    dst = wk;                mode = 2; break;
        default: src = Wv;   dst = wv;                mode = 2; break;
    }
    for (int i = blockIdx.x * 256 + threadIdx.x; i < 65536 / 4; i += 32 * 256) {
        float4 v = ((const float4*)src)[i];
        ushort4 o;
        if (mode == 1) {
            o.x = __builtin_bit_cast(u16, (f16)v.x);
            o.y = __builtin_bit_cast(u16, (f16)v.y);
            o.z = __builtin_bit_cast(u16, (f16)v.z);
            o.w = __builtin_bit_cast(u16, (f16)v.w);
        } else {
            o.x = f2b(v.x); o.y = f2b(v.y); o.z = f2b(v.z); o.w = f2b(v.w);
        }
        if (mode == 2) {
            ((ushort4*)dst)[i] = o;
        } else {
            int r = i >> 5, c4 = i & 31;                 // [512][128] view
            int rp = ((r & 127) << 2) | (r >> 7);        // u*4 + g
            *(ushort4*)&dst[rp * 128 + c4 * 4] = o;
        }
    }
}

// ---------------------------------------------------------------------------
// Shared MFMA GEMM core: C[M,N] = A[M,K]*Bt[N,K]^T, fp32 acc, bf16 out.
// 128x128 tile, BK=64, 256 thr = 4 waves (2x2), wave = 64x64.
// AFP32: A is fp32 in global, converted to bf16 during LDS staging.
// MODE 0: row-major store, no bias. MODE 1: xg store [s][b][col] + bias
// (bias index un-permuted since cols are gate-interleaved).
// TRANSGRID: remap the fixed (256,2,z) launch grid so blockIdx.x indexes N
// and blockIdx.y indexes M (for the M=256 x N=32768 v^T GEMM).
// ---------------------------------------------------------------------------
template <int MODE, int AFP32, int TRANSGRID = 0>
__device__ __forceinline__ void gemm_core(
    const void* __restrict__ Araw, const u16* __restrict__ Bt,
    const float* __restrict__ bias1, const float* __restrict__ bias2,
    u16* __restrict__ Cout, int K, int N)
{
    __shared__ u16 As[128 * 72];
    __shared__ u16 Bs[128 * 72];
    const int tid = threadIdx.x;
    const int lane = tid & 63, wave = tid >> 6;
    const int wm = wave >> 1, wn = wave & 1;
    const int lo = lane & 15, hi = lane >> 4;
    const int m0 = (TRANSGRID ? blockIdx.y : blockIdx.x) * 128;
    const int n0 = (TRANSGRID ? blockIdx.x : blockIdx.y) * 128;

    f32x4 acc[4][4] = {};

    for (int k0 = 0; k0 < K; k0 += 64) {
        __syncthreads();
#pragma unroll
        for (int i = 0; i < 4; i++) {
            int c = tid + 256 * i;
            int row = c >> 3, kc = (c & 7) * 8;
            if (AFP32) {
                const float* ap = (const float*)Araw + (size_t)(m0 + row) * K + k0 + kc;
                float4 v0 = *(const float4*)ap;
                float4 v1 = *(const float4*)(ap + 4);
                uint4 o;
                o.x = (u32)f2b(v0.x) | ((u32)f2b(v0.y) << 16);
                o.y = (u32)f2b(v0.z) | ((u32)f2b(v0.w) << 16);
                o.z = (u32)f2b(v1.x) | ((u32)f2b(v1.y) << 16);
                o.w = (u32)f2b(v1.z) | ((u32)f2b(v1.w) << 16);
                *(uint4*)&As[row * 72 + kc] = o;
            } else {
                *(uint4*)&As[row * 72 + kc] =
                    *(const uint4*)&((const u16*)Araw)[(size_t)(m0 + row) * K + k0 + kc];
            }
            *(uint4*)&Bs[row * 72 + kc] =
                *(const uint4*)&Bt[(size_t)(n0 + row) * K + k0 + kc];
        }
        __syncthreads();
#pragma unroll
        for (int ks = 0; ks < 2; ks++) {
            bf16x8 af[4], bfr[4];
#pragma unroll
            for (int i = 0; i < 4; i++)
                af[i] = *(const bf16x8a*)&As[(wm * 64 + i * 16 + lo) * 72 + ks * 32 + hi * 8];
#pragma unroll
            for (int j = 0; j < 4; j++)
                bfr[j] = *(const bf16x8a*)&Bs[(wn * 64 + j * 16 + lo) * 72 + ks * 32 + hi * 8];
#pragma unroll
            for (int i = 0; i < 4; i++)
#pragma unroll
                for (int j = 0; j < 4; j++)
                    acc[i][j] = __builtin_amdgcn_mfma_f32_16x16x32_bf16(
                        af[i], bfr[j], acc[i][j], 0, 0, 0);
        }
    }
#pragma unroll
    for (int j = 0; j < 4; j++) {
        int col = n0 + wn * 64 + j * 16 + lo;
        float bsum = 0.f;
        if (MODE == 1) {
            int co = ((col & 3) << 7) | (col >> 2);   // un-permute for bias lookup
            bsum = bias1[co] + bias2[co];
        }
#pragma unroll
        for (int i = 0; i < 4; i++) {
            int row0 = m0 + wm * 64 + i * 16 + hi * 4;
#pragma unroll
            for (int r = 0; r < 4; r++) {
                float v = acc[i][j][r] + bsum;
                if (MODE == 1) {
                    int row = row0 + r;                 // = b*1024 + s
                    int sidx = row & 1023, bidx = row >> 10;
                    Cout[(size_t)sidx * (BB * 512) + bidx * 512 + col] = f2b(v);
                } else {
                    Cout[(size_t)(row0 + r) * N + col] = f2b(v);
                }
            }
        }
    }
}

// both xg directions in one launch (blockIdx.z = dir); A = x in fp32
__global__ __launch_bounds__(256) void gemm_xg(
    const float* __restrict__ A, const u16* __restrict__ Bt_f,
    const u16* __restrict__ Bt_b,
    const float* __restrict__ f_bih, const float* __restrict__ f_bhh,
    const float* __restrict__ b_bih, const float* __restrict__ b_bhh,
    u16* __restrict__ xg)
{
    const int dir = blockIdx.z;
    gemm_core<1, 1>(A, dir ? Bt_b : Bt_f,
                    dir ? b_bih : f_bih, dir ? b_bhh : f_bhh,
                    xg + (size_t)dir * SS * BB * 512, 128, 512);
}

// q,k,v^T in one launch (blockIdx.z selects).
// z=0/1: q,k = h @ W^T -> [32768][256] row-major (grid x=M-blocks, y=N-blocks).
// z=2:   vT = Wv @ h^T -> [256][32768] d-major (TRANSGRID: x=N-blocks,
//        y=M-blocks) — eliminates the separate transpose_v pass entirely
//        (r11: killed 48 MB of traffic + a launch; confirmed −20 us).
__global__ __launch_bounds__(256) void gemm_qkv(
    const u16* __restrict__ A, const u16* __restrict__ Wq,
    const u16* __restrict__ Wk, const u16* __restrict__ Wv,
    u16* __restrict__ qb, u16* __restrict__ kb, u16* __restrict__ vT)
{
    const int z = blockIdx.z;
    if (z == 2) {
        gemm_core<0, 0, 1>(Wv, A, nullptr, nullptr, vT, 256, BB * SS);
    } else {
        const u16* Bt = (z == 0) ? Wq : Wk;
        u16* out = (z == 0) ? qb : kb;
        gemm_core<0, 0>(A, Bt, nullptr, nullptr, out, 256, 256);
    }
}

// ---------------------------------------------------------------------------
// Split-K dot2 LSTM scan v6 (the verified best: ~530 us, step 1243 cyc,
// VGPR 132 = weights resident). 64 WGs (one per (dir,b) sequence),
// 256 thr = 4 waves = 1 wave/SIMD, waves_per_eu(1,1) — the only config
// whose regalloc verifiably holds the 128 weight words.
//
// Structural-floor verdict after r6-r9: same-chain TLP shares the serial
// chain (r1/r3); cross-chain wave-TLP spills at the (2,2) budget (r6);
// cross-chain ILP spills at the 132-reg wall AND halves CUs (r7); MFMA
// variants either waste 16x M-rows (r8) or starve CUs + uncoalesce xg
// (r9). v6's step = ds_read(h) -> 128 fdot2 -> DPP reduce -> activation
// chain -> ds_write -> lds_barrier, with 64 CUs active.
// ---------------------------------------------------------------------------
__global__ __launch_bounds__(256)
__attribute__((amdgpu_waves_per_eu(1, 1)))
void lstm_scan_sk(
    const u16* __restrict__ Whh_h,   // [2][512][128] f16, rows permuted
    const u16* __restrict__ xg,      // [2][S][B][512] bf16, cols permuted
    u16* __restrict__ hout)          // [B][S][256] bf16
{
    const int wg = blockIdx.x;       // 0..63
    const int dir = wg >> 5, b = wg & 31;
    const int t_ = threadIdx.x;      // 0..255
    const int u = t_ >> 1;           // unit 0..127
    const int kh = t_ & 1;           // K-half

    // resident weights: rows 4u..4u+3, K-half kh -> 128 u32 in VGPRs.
    u32 w[4][32];
    {
        const volatile u32* vp = (const volatile u32*)(Whh_h + (size_t)dir * 512 * 128);
#pragma unroll
        for (int g = 0; g < 4; g++) {
            int base = ((4 * u + g) * 128 + kh * 64) >> 1;   // u32 index
#pragma unroll
            for (int k = 0; k < 32; k++) w[g][k] = vp[base + k];
        }
    }

    __shared__ __align__(16) u16 hbuf[2][128];   // f16 bits, double-buffered
    if (t_ < 128) hbuf[0][t_] = 0;
    float c = 0.0f;

    const u16* xgp = xg + (size_t)dir * SS * (BB * 512) + (size_t)b * 512 + 4 * u;
    u16* hop = hout + (size_t)b * SS * DD + dir * HH + u;

    int s = dir ? (SS - 1) : 0;
    const int d1 = dir ? -1 : 1;
    uint2 nxA = *(const uint2*)&xgp[(size_t)s * (BB * 512)];         // step 0
    uint2 nxB = *(const uint2*)&xgp[(size_t)(s + d1) * (BB * 512)];  // step 1
    lds_barrier();

    // one LSTM step; nx holds this step's xg, refilled for step t+2.
    auto body = [&](uint2& nx, int parity) {
        uint2 xv = nx;                      // counted vmcnt wait (~2 steps slack)
        int sp = s + 2 * d1;                // depth-2 prefetch, issued EARLY
        if ((unsigned)sp < SS)
            nx = *(const uint2*)&xgp[(size_t)sp * (BB * 512)];

        const uint4* hb = (const uint4*)&hbuf[parity][kh * 64];
        float g0 = 0.f, g1 = 0.f, g2 = 0.f, g3 = 0.f;   // 4 chains (one per gate)
#pragma unroll
        for (int cc = 0; cc < 8; cc++) {
            uint4 hh = hb[cc];                           // broadcast read (free)
            u32 hv[4] = {hh.x, hh.y, hh.z, hh.w};
#pragma unroll
            for (int j = 0; j < 4; j++) {
                f16x2 hp = __builtin_bit_cast(f16x2, hv[j]);
                g0 = __builtin_amdgcn_fdot2(hp, __builtin_bit_cast(f16x2, w[0][4 * cc + j]), g0, false);
                g1 = __builtin_amdgcn_fdot2(hp, __builtin_bit_cast(f16x2, w[1][4 * cc + j]), g1, false);
                g2 = __builtin_amdgcn_fdot2(hp, __builtin_bit_cast(f16x2, w[2][4 * cc + j]), g2, false);
                g3 = __builtin_amdgcn_fdot2(hp, __builtin_bit_cast(f16x2, w[3][4 * cc + j]), g3, false);
            }
        }
        // cross-half butterfly reduce on the VALU pipe: ONE DPP level (lane^1)
        g0 += dpp_mov<0xB1>(g0);
        g1 += dpp_mov<0xB1>(g1);
        g2 += dpp_mov<0xB1>(g2);
        g3 += dpp_mov<0xB1>(g3);
        // add xg (gates i,f,g~,o = permuted cols 4u..4u+3)
        g0 += b2f((u16)(xv.x & 0xffff)); g1 += b2f((u16)(xv.x >> 16));
        g2 += b2f((u16)(xv.y & 0xffff)); g3 += b2f((u16)(xv.y >> 16));

        c = fmaf(sig_fast(g1), c, sig_fast(g0) * tanh_fast(g2));
        float h = sig_fast(g3) * tanh_fast(c);

        if (kh == 0)
            hbuf[parity ^ 1][u] = __builtin_bit_cast(u16, (f16)h);
        else
            hop[(size_t)s * DD] = f2b(h);
        lds_barrier();                      // LDS-only drain; vmem stays in flight
        s += d1;
    };

    for (int t = 0; t < SS; t += 2) {
        body(nxA, 0);
        body(nxB, 1);
    }
}

// ---------------------------------------------------------------------------
// Flash attention (r15 configuration — the verified best, 734.5 us total).
// r16 postmortem: KV-tile 64 pushed static LDS to ~78 KB/WG; with alloc
// granularity 2 WGs no longer fit the 160 KiB pool -> 1 WG/CU -> attn lost
// its co-resident latency-hiding partner and the grid serialized into two
// passes (+109 us). Reverted. LDS growth past ~half the pool is a cliff at
// this 512-WG/256-CU grid shape.
// Structure: KV tile 32, XCD-swizzled 1D grid (T1), DPP softmax reduces
// (VALU pipe, r13: −6 us), NO mid-tile barrier (Ps RAW is same-wave only,
// r15: −4 us), V from d-major vT, s_setprio around MFMA clusters (T5).
// f32 out.
// ---------------------------------------------------------------------------
__global__ __launch_bounds__(256) void attn_kernel(
    const u16* __restrict__ q, const u16* __restrict__ k,
    const u16* __restrict__ vT, float* __restrict__ out)
{
    __shared__ u16 Ks[32 * 264];
    __shared__ u16 Vs[256 * 40];
    __shared__ u16 Ps[64 * 40];
    const int bid = blockIdx.x;                  // 0..511
    const int b = (bid & 7) * 4 + (bid >> 7);    // batch: XCD-pinned
    const int q0 = ((bid >> 3) & 15) * 64;       // q tile
    const int tid = threadIdx.x, wave = tid >> 6, lane = tid & 63;
    const int lo = lane & 15, hi = lane >> 4;
    const float c1 = 0.09016844005556021f;  // log2(e)/16

    bf16x8 qf[8];
    {
        const u16* qp = q + ((size_t)b * SS + q0 + wave * 16 + lo) * DD;
#pragma unroll
        for (int ks = 0; ks < 8; ks++)
            qf[ks] = *(const bf16x8a*)&qp[ks * 32 + hi * 8];
    }
    float m_i[4] = {-1e30f, -1e30f, -1e30f, -1e30f};
    float l_i[4] = {0.f, 0.f, 0.f, 0.f};
    f32x4 o[16] = {};

    for (int t0 = 0; t0 < SS; t0 += 32) {
        __syncthreads();
#pragma unroll
        for (int i = 0; i < 4; i++) {
            int c = tid + 256 * i;
            {
                int row = c >> 5, dc = (c & 31) * 8;
                *(uint4*)&Ks[row * 264 + dc] =
                    *(const uint4*)&k[((size_t)b * SS + t0 + row) * DD + dc];
            }
            {
                int d = c >> 2, sc = (c & 3) * 8;
                *(uint4*)&Vs[d * 40 + sc] =
                    *(const uint4*)&vT[(size_t)d * (BB * SS) + b * SS + t0 + sc];
            }
        }
        __syncthreads();

        f32x4 sacc[2] = {};
        __builtin_amdgcn_s_setprio(1);
#pragma unroll
        for (int ks = 0; ks < 8; ks++) {
#pragma unroll
            for (int j = 0; j < 2; j++) {
                bf16x8 bfr = *(const bf16x8a*)&Ks[(j * 16 + lo) * 264 + ks * 32 + hi * 8];
                sacc[j] = __builtin_amdgcn_mfma_f32_16x16x32_bf16(qf[ks], bfr, sacc[j], 0, 0, 0);
            }
        }
        __builtin_amdgcn_s_setprio(0);

        float tt[2][4];
#pragma unroll
        for (int j = 0; j < 2; j++)
#pragma unroll
            for (int r = 0; r < 4; r++) tt[j][r] = sacc[j][r] * c1;
        // 16-lane max reduce on the VALU pipe (DPP): xor1, xor2, ror4, ror8
        float rm[4];
#pragma unroll
        for (int r = 0; r < 4; r++) rm[r] = fmaxf(tt[0][r], tt[1][r]);
#pragma unroll
        for (int r = 0; r < 4; r++) rm[r] = fmaxf(rm[r], dpp_mov<0xB1>(rm[r]));
#pragma unroll
        for (int r = 0; r < 4; r++) rm[r] = fmaxf(rm[r], dpp_mov<0x4E>(rm[r]));
#pragma unroll
        for (int r = 0; r < 4; r++) rm[r] = fmaxf(rm[r], dpp_mov<0x124>(rm[r]));
#pragma unroll
        for (int r = 0; r < 4; r++) rm[r] = fmaxf(rm[r], dpp_mov<0x128>(rm[r]));
        float al[4], rs[4];
#pragma unroll
        for (int r = 0; r < 4; r++) {
            float mn = fmaxf(m_i[r], rm[r]);
            al[r] = __builtin_amdgcn_exp2f(m_i[r] - mn);
            m_i[r] = mn;
            rs[r] = 0.f;
        }
#pragma unroll
        for (int j = 0; j < 2; j++)
#pragma unroll
            for (int r = 0; r < 4; r++) {
                float p = __builtin_amdgcn_exp2f(tt[j][r] - m_i[r]);
                rs[r] += p;
                Ps[(wave * 16 + hi * 4 + r) * 40 + j * 16 + lo] = f2b(p);
            }
        // 16-lane sum reduce on the VALU pipe (DPP)
#pragma unroll
        for (int r = 0; r < 4; r++) rs[r] += dpp_mov<0xB1>(rs[r]);
#pragma unroll
        for (int r = 0; r < 4; r++) rs[r] += dpp_mov<0x4E>(rs[r]);
#pragma unroll
        for (int r = 0; r < 4; r++) rs[r] += dpp_mov<0x124>(rs[r]);
#pragma unroll
        for (int r = 0; r < 4; r++) rs[r] += dpp_mov<0x128>(rs[r]);
#pragma unroll
        for (int r = 0; r < 4; r++) l_i[r] = l_i[r] * al[r] + rs[r];
#pragma unroll
        for (int nt = 0; nt < 16; nt++) {
            o[nt][0] *= al[0]; o[nt][1] *= al[1];
            o[nt][2] *= al[2]; o[nt][3] *= al[3];
        }
        // NO barrier here: Ps RAW is same-wave only (r15 verified); the DS
        // pipe is in-order per wave and the compiler inserts the lgkmcnt.
        bf16x8 pa = *(const bf16x8a*)&Ps[(wave * 16 + lo) * 40 + hi * 8];
        __builtin_amdgcn_s_setprio(1);
#pragma unroll
        for (int nt = 0; nt < 16; nt++) {
            bf16x8 bv = *(const bf16x8a*)&Vs[(nt * 16 + lo) * 40 + hi * 8];
            o[nt] = __builtin_amdgcn_mfma_f32_16x16x32_bf16(pa, bv, o[nt], 0, 0, 0);
        }
        __builtin_amdgcn_s_setprio(0);
    }
    float inv[4];
#pragma unroll
    for (int r = 0; r < 4; r++) inv[r] = __builtin_amdgcn_rcpf(l_i[r]);
#pragma unroll
    for (int nt = 0; nt < 16; nt++)
#pragma unroll
        for (int r = 0; r < 4; r++) {
            int row = q0 + wave * 16 + hi * 4 + r;
            int col = nt * 16 + lo;
            out[((size_t)b * SS + row) * DD + col] = o[nt][r] * inv[r];
        }
}

// ---------------------------------------------------------------------------
extern "C" void kernel_launch(void* const* d_in, const int* in_sizes, int n_in,
                              void* d_out, int out_size, void* d_ws, size_t ws_size,
                              hipStream_t stream)
{
    (void)in_sizes; (void)n_in; (void)out_size;
    const float* x      = (const float*)d_in[0];
    const float* fw_Wih = (const float*)d_in[1];
    const float* fw_Whh = (const float*)d_in[2];
    const float* fw_bih = (const float*)d_in[3];
    const float* fw_bhh = (const float*)d_in[4];
    const float* bw_Wih = (const float*)d_in[5];
    const float* bw_Whh = (const float*)d_in[6];
    const float* bw_bih = (const float*)d_in[7];
    const float* bw_bhh = (const float*)d_in[8];
    const float* Wq = (const float*)d_in[9];
    const float* Wk = (const float*)d_in[10];
    const float* Wv = (const float*)d_in[11];

    // Workspace layout (total 143,523,840 B; ws proven >= 201 MB in r1/r2):
    //   [0, 67108864)    xg bf16 [2][S][B][512], cols gate-interleaved
    //                    (dead after scan)
    //   +67108864        h   bf16 [32768][256]
    //   +83886080        qb   +100663296 kb   +117440512 vT [256][32768]
    //   +142606336       weights: fwWih_p, bwWih_p, wq, wk, wv (bf16),
    //                    Whh f16 permuted [2][512][128]
    if (ws_size < 143523840ULL) return;

    char* ws = (char*)d_ws;
    u16* xg  = (u16*)ws;
    u16* h   = (u16*)(ws + 67108864);
    u16* qb  = (u16*)(ws + 83886080);
    u16* kb  = (u16*)(ws + 100663296);
    u16* vT  = (u16*)(ws + 117440512);
    u16* wfih16 = (u16*)(ws + 142606336);
    u16* wbih16 = (u16*)(ws + 142606336 + 131072);
    u16* wq16   = (u16*)(ws + 142606336 + 262144);
    u16* wk16   = (u16*)(ws + 142606336 + 393216);
    u16* wv16   = (u16*)(ws + 142606336 + 524288);
    u16* whhf16 = (u16*)(ws + 142606336 + 655360);   // [2][512][128] f16

    conv_weights<<<dim3(32, 7), 256, 0, stream>>>(
        fw_Wih, bw_Wih, fw_Whh, bw_Whh, Wq, Wk, Wv,
        wfih16, wbih16, whhf16, wq16, wk16, wv16);

    // xg = x @ Wih_p^T + biases -> [s][b][512] permuted-col layout (both dirs);
    // x is fp32, converted to bf16 during LDS staging
    gemm_xg<<<dim3(256, 4, 2), 256, 0, stream>>>(
        x, wfih16, wbih16, fw_bih, fw_bhh, bw_bih, bw_bhh, xg);
    // split-K dot2 scan v6 (verified best: ~530 us), 64 WGs
    lstm_scan_sk<<<64, 256, 0, stream>>>(whhf16, xg, h);
    // q,k (row-major) and v^T (d-major, direct — no transpose pass)
    gemm_qkv<<<dim3(256, 2, 3), 256, 0, stream>>>(h, wq16, wk16, wv16, qb, kb, vT);
    // fused attention -> out fp32 (r15 best configuration)
    attn_kernel<<<512, 256, 0, stream>>>(qb, kb, vT, (float*)d_out);
}

// Round 18
// 729.297 us; speedup vs baseline: 1.1568x; 1.0076x over previous
//
#include <hip/hip_runtime.h>

typedef unsigned short u16;
typedef unsigned int u32;
typedef __bf16 bf16x8 __attribute__((ext_vector_type(8)));
typedef bf16x8 __attribute__((may_alias)) bf16x8a;   // TBAA-safe vector loads
typedef float f32x4 __attribute__((ext_vector_type(4)));
typedef _Float16 f16;
typedef _Float16 f16x2 __attribute__((ext_vector_type(2)));

#define BB 32
#define SS 1024
#define HH 128
#define DD 256

__device__ __forceinline__ float b2f(u16 u) {
    u32 v = ((u32)u) << 16;
    return __builtin_bit_cast(float, v);
}
__device__ __forceinline__ u16 f2b(float f) {
    u32 u = __builtin_bit_cast(u32, f);
    u32 r = (u + 0x7fffu + ((u >> 16) & 1u)) >> 16;   // RNE
    return (u16)r;
}
__device__ __forceinline__ float sig_fast(float x) {
    return __builtin_amdgcn_rcpf(1.0f + __builtin_amdgcn_exp2f(-1.4426950408889634f * x));
}
__device__ __forceinline__ float tanh_fast(float x) {
    return 2.0f * sig_fast(2.0f * x) - 1.0f;
}
// DPP lane-permute move (VALU pipe, no LDS). CTRLs used:
//   0xB1 = quad_perm(1,0,3,2)  = xor1      0x4E = quad_perm(2,3,0,1) = xor2
//   0x124 = row_ror:4          0x128 = row_ror:8   (16-lane-row rotations)
// 16-lane butterfly reduce: xor1, xor2 (quads uniform), then ror4 (+quad+1),
// ror8 (+quad+2,+3) — valid for any commutative/associative op.
template <int CTRL>
__device__ __forceinline__ float dpp_mov(float x) {
    return __builtin_bit_cast(float,
        __builtin_amdgcn_update_dpp(0, __builtin_bit_cast(int, x),
                                    CTRL, 0xF, 0xF, true));
}
// Raw workgroup barrier that drains ONLY the LDS pipe (lgkmcnt). Unlike
// __syncthreads(), which emits s_waitcnt vmcnt(0) lgkmcnt(0) before
// s_barrier, this leaves global loads/stores in flight across the barrier
// (r4: confirmed real, −160 cyc/step). "memory" clobber pins compiler-side
// ordering of the LDS ops. (Used in the SCAN only — r12 showed bundling it
// into attn correlated with a regression.)
__device__ __forceinline__ void lds_barrier() {
    asm volatile("s_waitcnt lgkmcnt(0)\n\ts_barrier" ::: "memory");
}

// ---------------------------------------------------------------------------
// All 7 weight conversions in ONE kernel (each matrix = 65536 elements).
// mode 0: gate-perm (row g*128+u -> u*4+g), bf16   (Wih for xg GEMM)
// mode 1: gate-perm, f16                           (Whh for scan dot2)
// mode 2: plain, bf16                              (Wq/Wk/Wv)
// ---------------------------------------------------------------------------
__global__ __launch_bounds__(256) void conv_weights(
    const float* __restrict__ fwWih, const float* __restrict__ bwWih,
    const float* __restrict__ fwWhh, const float* __restrict__ bwWhh,
    const float* __restrict__ Wq, const float* __restrict__ Wk,
    const float* __restrict__ Wv,
    u16* __restrict__ wfih, u16* __restrict__ wbih, u16* __restrict__ whhf,
    u16* __restrict__ wq, u16* __restrict__ wk, u16* __restrict__ wv)
{
    const int which = blockIdx.y;
    const float* src; u16* dst; int mode;
    switch (which) {
        case 0: src = fwWih; dst = wfih;              mode = 0; break;
        case 1: src = bwWih; dst = wbih;              mode = 0; break;
        case 2: src = fwWhh; dst = whhf;              mode = 1; break;
        case 3: src = bwWhh; dst = whhf + 512 * 128;  mode = 1; break;
        case 4: src = Wq;    dst = wq;                mode = 2; break;
        case 5: src = Wk;    dst = wk;                mode = 2; break;
        default: src = Wv;   dst = wv;                mode = 2; break;
    }
    for (int i = blockIdx.x * 256 + threadIdx.x; i < 65536 / 4; i += 32 * 256) {
        float4 v = ((const float4*)src)[i];
        ushort4 o;
        if (mode == 1) {
            o.x = __builtin_bit_cast(u16, (f16)v.x);
            o.y = __builtin_bit_cast(u16, (f16)v.y);
            o.z = __builtin_bit_cast(u16, (f16)v.z);
            o.w = __builtin_bit_cast(u16, (f16)v.w);
        } else {
            o.x = f2b(v.x); o.y = f2b(v.y); o.z = f2b(v.z); o.w = f2b(v.w);
        }
        if (mode == 2) {
            ((ushort4*)dst)[i] = o;
        } else {
            int r = i >> 5, c4 = i & 31;                 // [512][128] view
            int rp = ((r & 127) << 2) | (r >> 7);        // u*4 + g
            *(ushort4*)&dst[rp * 128 + c4 * 4] = o;
        }
    }
}

// ---------------------------------------------------------------------------
// Shared MFMA GEMM core: C[M,N] = A[M,K]*Bt[N,K]^T, fp32 acc, bf16 out.
// 128x128 tile, BK=64, 256 thr = 4 waves (2x2), wave = 64x64.
// AFP32: A is fp32 in global, converted to bf16 during LDS staging.
// MODE 0: row-major store, no bias. MODE 1: xg store [s][b][col] + bias
// (bias index un-permuted since cols are gate-interleaved).
// TRANSGRID: remap the fixed (256,2,z) launch grid so blockIdx.x indexes N
// and blockIdx.y indexes M (for the M=256 x N=32768 v^T GEMM).
// ---------------------------------------------------------------------------
template <int MODE, int AFP32, int TRANSGRID = 0>
__device__ __forceinline__ void gemm_core(
    const void* __restrict__ Araw, const u16* __restrict__ Bt,
    const float* __restrict__ bias1, const float* __restrict__ bias2,
    u16* __restrict__ Cout, int K, int N)
{
    __shared__ u16 As[128 * 72];
    __shared__ u16 Bs[128 * 72];
    const int tid = threadIdx.x;
    const int lane = tid & 63, wave = tid >> 6;
    const int wm = wave >> 1, wn = wave & 1;
    const int lo = lane & 15, hi = lane >> 4;
    const int m0 = (TRANSGRID ? blockIdx.y : blockIdx.x) * 128;
    const int n0 = (TRANSGRID ? blockIdx.x : blockIdx.y) * 128;

    f32x4 acc[4][4] = {};

    for (int k0 = 0; k0 < K; k0 += 64) {
        __syncthreads();
#pragma unroll
        for (int i = 0; i < 4; i++) {
            int c = tid + 256 * i;
            int row = c >> 3, kc = (c & 7) * 8;
            if (AFP32) {
                const float* ap = (const float*)Araw + (size_t)(m0 + row) * K + k0 + kc;
                float4 v0 = *(const float4*)ap;
                float4 v1 = *(const float4*)(ap + 4);
                uint4 o;
                o.x = (u32)f2b(v0.x) | ((u32)f2b(v0.y) << 16);
                o.y = (u32)f2b(v0.z) | ((u32)f2b(v0.w) << 16);
                o.z = (u32)f2b(v1.x) | ((u32)f2b(v1.y) << 16);
                o.w = (u32)f2b(v1.z) | ((u32)f2b(v1.w) << 16);
                *(uint4*)&As[row * 72 + kc] = o;
            } else {
                *(uint4*)&As[row * 72 + kc] =
                    *(const uint4*)&((const u16*)Araw)[(size_t)(m0 + row) * K + k0 + kc];
            }
            *(uint4*)&Bs[row * 72 + kc] =
                *(const uint4*)&Bt[(size_t)(n0 + row) * K + k0 + kc];
        }
        __syncthreads();
#pragma unroll
        for (int ks = 0; ks < 2; ks++) {
            bf16x8 af[4], bfr[4];
#pragma unroll
            for (int i = 0; i < 4; i++)
                af[i] = *(const bf16x8a*)&As[(wm * 64 + i * 16 + lo) * 72 + ks * 32 + hi * 8];
#pragma unroll
            for (int j = 0; j < 4; j++)
                bfr[j] = *(const bf16x8a*)&Bs[(wn * 64 + j * 16 + lo) * 72 + ks * 32 + hi * 8];
#pragma unroll
            for (int i = 0; i < 4; i++)
#pragma unroll
                for (int j = 0; j < 4; j++)
                    acc[i][j] = __builtin_amdgcn_mfma_f32_16x16x32_bf16(
                        af[i], bfr[j], acc[i][j], 0, 0, 0);
        }
    }
#pragma unroll
    for (int j = 0; j < 4; j++) {
        int col = n0 + wn * 64 + j * 16 + lo;
        float bsum = 0.f;
        if (MODE == 1) {
            int co = ((col & 3) << 7) | (col >> 2);   // un-permute for bias lookup
            bsum = bias1[co] + bias2[co];
        }
#pragma unroll
        for (int i = 0; i < 4; i++) {
            int row0 = m0 + wm * 64 + i * 16 + hi * 4;
#pragma unroll
            for (int r = 0; r < 4; r++) {
                float v = acc[i][j][r] + bsum;
                if (MODE == 1) {
                    int row = row0 + r;                 // = b*1024 + s
                    int sidx = row & 1023, bidx = row >> 10;
                    Cout[(size_t)sidx * (BB * 512) + bidx * 512 + col] = f2b(v);
                } else {
                    Cout[(size_t)(row0 + r) * N + col] = f2b(v);
                }
            }
        }
    }
}

// both xg directions in one launch (blockIdx.z = dir); A = x in fp32
__global__ __launch_bounds__(256) void gemm_xg(
    const float* __restrict__ A, const u16* __restrict__ Bt_f,
    const u16* __restrict__ Bt_b,
    const float* __restrict__ f_bih, const float* __restrict__ f_bhh,
    const float* __restrict__ b_bih, const float* __restrict__ b_bhh,
    u16* __restrict__ xg)
{
    const int dir = blockIdx.z;
    gemm_core<1, 1>(A, dir ? Bt_b : Bt_f,
                    dir ? b_bih : f_bih, dir ? b_bhh : f_bhh,
                    xg + (size_t)dir * SS * BB * 512, 128, 512);
}

// q,k,v^T in one launch (blockIdx.z selects).
// z=0/1: q,k = h @ W^T -> [32768][256] row-major (grid x=M-blocks, y=N-blocks).
// z=2:   vT = Wv @ h^T -> [256][32768] d-major (TRANSGRID: x=N-blocks,
//        y=M-blocks) — eliminates the separate transpose_v pass entirely
//        (r11: killed 48 MB of traffic + a launch; confirmed −20 us).
__global__ __launch_bounds__(256) void gemm_qkv(
    const u16* __restrict__ A, const u16* __restrict__ Wq,
    const u16* __restrict__ Wk, const u16* __restrict__ Wv,
    u16* __restrict__ qb, u16* __restrict__ kb, u16* __restrict__ vT)
{
    const int z = blockIdx.z;
    if (z == 2) {
        gemm_core<0, 0, 1>(Wv, A, nullptr, nullptr, vT, 256, BB * SS);
    } else {
        const u16* Bt = (z == 0) ? Wq : Wk;
        u16* out = (z == 0) ? qb : kb;
        gemm_core<0, 0>(A, Bt, nullptr, nullptr, out, 256, 256);
    }
}

// ---------------------------------------------------------------------------
// Split-K dot2 LSTM scan v6 (the verified best: ~530 us, step 1243 cyc,
// VGPR 132 = weights resident). 64 WGs (one per (dir,b) sequence),
// 256 thr = 4 waves = 1 wave/SIMD, waves_per_eu(1,1) — the only config
// whose regalloc verifiably holds the 128 weight words.
//
// Structural-floor verdict after r6-r9: 512 cyc/step is the hard per-CU
// fdot2 issue floor (65536 MACs / 128 MACs-per-cyc); the residual is
// un-hideable (64 seqs x 1 WG/CU = no independent co-resident chain;
// same-chain TLP shares the chain r1/r3; cross-chain TLP/ILP spill
// r6/r7; MFMA wastes M-rows or starves CUs r8/r9).
// ---------------------------------------------------------------------------
__global__ __launch_bounds__(256)
__attribute__((amdgpu_waves_per_eu(1, 1)))
void lstm_scan_sk(
    const u16* __restrict__ Whh_h,   // [2][512][128] f16, rows permuted
    const u16* __restrict__ xg,      // [2][S][B][512] bf16, cols permuted
    u16* __restrict__ hout)          // [B][S][256] bf16
{
    const int wg = blockIdx.x;       // 0..63
    const int dir = wg >> 5, b = wg & 31;
    const int t_ = threadIdx.x;      // 0..255
    const int u = t_ >> 1;           // unit 0..127
    const int kh = t_ & 1;           // K-half

    // resident weights: rows 4u..4u+3, K-half kh -> 128 u32 in VGPRs.
    u32 w[4][32];
    {
        const volatile u32* vp = (const volatile u32*)(Whh_h + (size_t)dir * 512 * 128);
#pragma unroll
        for (int g = 0; g < 4; g++) {
            int base = ((4 * u + g) * 128 + kh * 64) >> 1;   // u32 index
#pragma unroll
            for (int k = 0; k < 32; k++) w[g][k] = vp[base + k];
        }
    }

    __shared__ __align__(16) u16 hbuf[2][128];   // f16 bits, double-buffered
    if (t_ < 128) hbuf[0][t_] = 0;
    float c = 0.0f;

    const u16* xgp = xg + (size_t)dir * SS * (BB * 512) + (size_t)b * 512 + 4 * u;
    u16* hop = hout + (size_t)b * SS * DD + dir * HH + u;

    int s = dir ? (SS - 1) : 0;
    const int d1 = dir ? -1 : 1;
    uint2 nxA = *(const uint2*)&xgp[(size_t)s * (BB * 512)];         // step 0
    uint2 nxB = *(const uint2*)&xgp[(size_t)(s + d1) * (BB * 512)];  // step 1
    lds_barrier();

    // one LSTM step; nx holds this step's xg, refilled for step t+2.
    auto body = [&](uint2& nx, int parity) {
        uint2 xv = nx;                      // counted vmcnt wait (~2 steps slack)
        int sp = s + 2 * d1;                // depth-2 prefetch, issued EARLY
        if ((unsigned)sp < SS)
            nx = *(const uint2*)&xgp[(size_t)sp * (BB * 512)];

        const uint4* hb = (const uint4*)&hbuf[parity][kh * 64];
        float g0 = 0.f, g1 = 0.f, g2 = 0.f, g3 = 0.f;   // 4 chains (one per gate)
#pragma unroll
        for (int cc = 0; cc < 8; cc++) {
            uint4 hh = hb[cc];                           // broadcast read (free)
            u32 hv[4] = {hh.x, hh.y, hh.z, hh.w};
#pragma unroll
            for (int j = 0; j < 4; j++) {
                f16x2 hp = __builtin_bit_cast(f16x2, hv[j]);
                g0 = __builtin_amdgcn_fdot2(hp, __builtin_bit_cast(f16x2, w[0][4 * cc + j]), g0, false);
                g1 = __builtin_amdgcn_fdot2(hp, __builtin_bit_cast(f16x2, w[1][4 * cc + j]), g1, false);
                g2 = __builtin_amdgcn_fdot2(hp, __builtin_bit_cast(f16x2, w[2][4 * cc + j]), g2, false);
                g3 = __builtin_amdgcn_fdot2(hp, __builtin_bit_cast(f16x2, w[3][4 * cc + j]), g3, false);
            }
        }
        // cross-half butterfly reduce on the VALU pipe: ONE DPP level (lane^1)
        g0 += dpp_mov<0xB1>(g0);
        g1 += dpp_mov<0xB1>(g1);
        g2 += dpp_mov<0xB1>(g2);
        g3 += dpp_mov<0xB1>(g3);
        // add xg (gates i,f,g~,o = permuted cols 4u..4u+3)
        g0 += b2f((u16)(xv.x & 0xffff)); g1 += b2f((u16)(xv.x >> 16));
        g2 += b2f((u16)(xv.y & 0xffff)); g3 += b2f((u16)(xv.y >> 16));

        c = fmaf(sig_fast(g1), c, sig_fast(g0) * tanh_fast(g2));
        float h = sig_fast(g3) * tanh_fast(c);

        if (kh == 0)
            hbuf[parity ^ 1][u] = __builtin_bit_cast(u16, (f16)h);
        else
            hop[(size_t)s * DD] = f2b(h);
        lds_barrier();                      // LDS-only drain; vmem stays in flight
        s += d1;
    };

    for (int t = 0; t < SS; t += 2) {
        body(nxA, 0);
        body(nxB, 1);
    }
}

// ---------------------------------------------------------------------------
// Flash attention (r15 structure + T13 defer-max, THR=8 in exp2 domain).
// When the tile max grows by <= 8 for ALL rows of the wave (wave-uniform
// __all), keep the stale running max and SKIP the rescale pass (4 exp2 +
// 64 o-mults + 4 l-mults). P is then bounded by 2^8=256 — f32 o/l accum
// and bf16 Ps keep the same RELATIVE precision (softmax normalizes scale).
// First tile: m_i=-1e30 forces the rescale path (al=0 zeroes the empty o).
// Guide-verified technique (T13: +5% attn, data-independent, m214v23/m239).
// Rest unchanged: KV tile 32, XCD-swizzled grid (T1), DPP softmax reduces,
// NO mid-tile barrier (Ps same-wave only, r15), V from d-major vT,
// s_setprio (T5). f32 out.
// ---------------------------------------------------------------------------
__global__ __launch_bounds__(256) void attn_kernel(
    const u16* __restrict__ q, const u16* __restrict__ k,
    const u16* __restrict__ vT, float* __restrict__ out)
{
    __shared__ u16 Ks[32 * 264];
    __shared__ u16 Vs[256 * 40];
    __shared__ u16 Ps[64 * 40];
    const int bid = blockIdx.x;                  // 0..511
    const int b = (bid & 7) * 4 + (bid >> 7);    // batch: XCD-pinned
    const int q0 = ((bid >> 3) & 15) * 64;       // q tile
    const int tid = threadIdx.x, wave = tid >> 6, lane = tid & 63;
    const int lo = lane & 15, hi = lane >> 4;
    const float c1 = 0.09016844005556021f;  // log2(e)/16

    bf16x8 qf[8];
    {
        const u16* qp = q + ((size_t)b * SS + q0 + wave * 16 + lo) * DD;
#pragma unroll
        for (int ks = 0; ks < 8; ks++)
            qf[ks] = *(const bf16x8a*)&qp[ks * 32 + hi * 8];
    }
    float m_i[4] = {-1e30f, -1e30f, -1e30f, -1e30f};
    float l_i[4] = {0.f, 0.f, 0.f, 0.f};
    f32x4 o[16] = {};

    for (int t0 = 0; t0 < SS; t0 += 32) {
        __syncthreads();
#pragma unroll
        for (int i = 0; i < 4; i++) {
            int c = tid + 256 * i;
            {
                int row = c >> 5, dc = (c & 31) * 8;
                *(uint4*)&Ks[row * 264 + dc] =
                    *(const uint4*)&k[((size_t)b * SS + t0 + row) * DD + dc];
            }
            {
                int d = c >> 2, sc = (c & 3) * 8;
                *(uint4*)&Vs[d * 40 + sc] =
                    *(const uint4*)&vT[(size_t)d * (BB * SS) + b * SS + t0 + sc];
            }
        }
        __syncthreads();

        f32x4 sacc[2] = {};
        __builtin_amdgcn_s_setprio(1);
#pragma unroll
        for (int ks = 0; ks < 8; ks++) {
#pragma unroll
            for (int j = 0; j < 2; j++) {
                bf16x8 bfr = *(const bf16x8a*)&Ks[(j * 16 + lo) * 264 + ks * 32 + hi * 8];
                sacc[j] = __builtin_amdgcn_mfma_f32_16x16x32_bf16(qf[ks], bfr, sacc[j], 0, 0, 0);
            }
        }
        __builtin_amdgcn_s_setprio(0);

        float tt[2][4];
#pragma unroll
        for (int j = 0; j < 2; j++)
#pragma unroll
            for (int r = 0; r < 4; r++) tt[j][r] = sacc[j][r] * c1;
        // 16-lane max reduce on the VALU pipe (DPP): xor1, xor2, ror4, ror8
        float rm[4];
#pragma unroll
        for (int r = 0; r < 4; r++) rm[r] = fmaxf(tt[0][r], tt[1][r]);
#pragma unroll
        for (int r = 0; r < 4; r++) rm[r] = fmaxf(rm[r], dpp_mov<0xB1>(rm[r]));
#pragma unroll
        for (int r = 0; r < 4; r++) rm[r] = fmaxf(rm[r], dpp_mov<0x4E>(rm[r]));
#pragma unroll
        for (int r = 0; r < 4; r++) rm[r] = fmaxf(rm[r], dpp_mov<0x124>(rm[r]));
#pragma unroll
        for (int r = 0; r < 4; r++) rm[r] = fmaxf(rm[r], dpp_mov<0x128>(rm[r]));
        // T13 defer-max: skip rescale when max growth <= 8 (wave-uniform)
        bool ok = (rm[0] <= m_i[0] + 8.f) && (rm[1] <= m_i[1] + 8.f) &&
                  (rm[2] <= m_i[2] + 8.f) && (rm[3] <= m_i[3] + 8.f);
        if (!__all(ok)) {
            float al[4];
#pragma unroll
            for (int r = 0; r < 4; r++) {
                float mn = fmaxf(m_i[r], rm[r]);
                al[r] = __builtin_amdgcn_exp2f(m_i[r] - mn);
                m_i[r] = mn;
                l_i[r] *= al[r];
            }
#pragma unroll
            for (int nt = 0; nt < 16; nt++) {
                o[nt][0] *= al[0]; o[nt][1] *= al[1];
                o[nt][2] *= al[2]; o[nt][3] *= al[3];
            }
        }
        float rs[4] = {0.f, 0.f, 0.f, 0.f};
#pragma unroll
        for (int j = 0; j < 2; j++)
#pragma unroll
            for (int r = 0; r < 4; r++) {
                float p = __builtin_amdgcn_exp2f(tt[j][r] - m_i[r]);   // <= 2^8
                rs[r] += p;
                Ps[(wave * 16 + hi * 4 + r) * 40 + j * 16 + lo] = f2b(p);
            }
        // 16-lane sum reduce on the VALU pipe (DPP)
#pragma unroll
        for (int r = 0; r < 4; r++) rs[r] += dpp_mov<0xB1>(rs[r]);
#pragma unroll
        for (int r = 0; r < 4; r++) rs[r] += dpp_mov<0x4E>(rs[r]);
#pragma unroll
        for (int r = 0; r < 4; r++) rs[r] += dpp_mov<0x124>(rs[r]);
#pragma unroll
        for (int r = 0; r < 4; r++) rs[r] += dpp_mov<0x128>(rs[r]);
#pragma unroll
        for (int r = 0; r < 4; r++) l_i[r] += rs[r];
        // NO barrier here: Ps RAW is same-wave only (r15 verified); the DS
        // pipe is in-order per wave and the compiler inserts the lgkmcnt.
        bf16x8 pa = *(const bf16x8a*)&Ps[(wave * 16 + lo) * 40 + hi * 8];
        __builtin_amdgcn_s_setprio(1);
#pragma unroll
        for (int nt = 0; nt < 16; nt++) {
            bf16x8 bv = *(const bf16x8a*)&Vs[(nt * 16 + lo) * 40 + hi * 8];
            o[nt] = __builtin_amdgcn_mfma_f32_16x16x32_bf16(pa, bv, o[nt], 0, 0, 0);
        }
        __builtin_amdgcn_s_setprio(0);
    }
    float inv[4];
#pragma unroll
    for (int r = 0; r < 4; r++) inv[r] = __builtin_amdgcn_rcpf(l_i[r]);
#pragma unroll
    for (int nt = 0; nt < 16; nt++)
#pragma unroll
        for (int r = 0; r < 4; r++) {
            int row = q0 + wave * 16 + hi * 4 + r;
            int col = nt * 16 + lo;
            out[((size_t)b * SS + row) * DD + col] = o[nt][r] * inv[r];
        }
}

// ---------------------------------------------------------------------------
extern "C" void kernel_launch(void* const* d_in, const int* in_sizes, int n_in,
                              void* d_out, int out_size, void* d_ws, size_t ws_size,
                              hipStream_t stream)
{
    (void)in_sizes; (void)n_in; (void)out_size;
    const float* x      = (const float*)d_in[0];
    const float* fw_Wih = (const float*)d_in[1];
    const float* fw_Whh = (const float*)d_in[2];
    const float* fw_bih = (const float*)d_in[3];
    const float* fw_bhh = (const float*)d_in[4];
    const float* bw_Wih = (const float*)d_in[5];
    const float* bw_Whh = (const float*)d_in[6];
    const float* bw_bih = (const float*)d_in[7];
    const float* bw_bhh = (const float*)d_in[8];
    const float* Wq = (const float*)d_in[9];
    const float* Wk = (const float*)d_in[10];
    const float* Wv = (const float*)d_in[11];

    // Workspace layout (total 143,523,840 B; ws proven >= 201 MB in r1/r2):
    //   [0, 67108864)    xg bf16 [2][S][B][512], cols gate-interleaved
    //                    (dead after scan)
    //   +67108864        h   bf16 [32768][256]
    //   +83886080        qb   +100663296 kb   +117440512 vT [256][32768]
    //   +142606336       weights: fwWih_p, bwWih_p, wq, wk, wv (bf16),
    //                    Whh f16 permuted [2][512][128]
    if (ws_size < 143523840ULL) return;

    char* ws = (char*)d_ws;
    u16* xg  = (u16*)ws;
    u16* h   = (u16*)(ws + 67108864);
    u16* qb  = (u16*)(ws + 83886080);
    u16* kb  = (u16*)(ws + 100663296);
    u16* vT  = (u16*)(ws + 117440512);
    u16* wfih16 = (u16*)(ws + 142606336);
    u16* wbih16 = (u16*)(ws + 142606336 + 131072);
    u16* wq16   = (u16*)(ws + 142606336 + 262144);
    u16* wk16   = (u16*)(ws + 142606336 + 393216);
    u16* wv16   = (u16*)(ws + 142606336 + 524288);
    u16* whhf16 = (u16*)(ws + 142606336 + 655360);   // [2][512][128] f16

    conv_weights<<<dim3(32, 7), 256, 0, stream>>>(
        fw_Wih, bw_Wih, fw_Whh, bw_Whh, Wq, Wk, Wv,
        wfih16, wbih16, whhf16, wq16, wk16, wv16);

    // xg = x @ Wih_p^T + biases -> [s][b][512] permuted-col layout (both dirs);
    // x is fp32, converted to bf16 during LDS staging
    gemm_xg<<<dim3(256, 4, 2), 256, 0, stream>>>(
        x, wfih16, wbih16, fw_bih, fw_bhh, bw_bih, bw_bhh, xg);
    // split-K dot2 scan v6 (verified best: ~530 us), 64 WGs
    lstm_scan_sk<<<64, 256, 0, stream>>>(whhf16, xg, h);
    // q,k (row-major) and v^T (d-major, direct — no transpose pass)
    gemm_qkv<<<dim3(256, 2, 3), 256, 0, stream>>>(h, wq16, wk16, wv16, qb, kb, vT);
    // fused attention -> out fp32 (r15 + T13 defer-max)
    attn_kernel<<<512, 256, 0, stream>>>(qb, kb, vT, (float*)d_out);
}